// Round 8
// baseline (230.449 us; speedup 1.0000x reference)
//
#include <hip/hip_runtime.h>
#include <hip/hip_cooperative_groups.h>
#include <math.h>

namespace cg = cooperative_groups;

#define E 8
#define DF 512
#define DE 128
#define H 8
#define S 64
#define GH 16
#define HD 16
#define B 2
#define NTOK 1024
#define QT 2          // query chunks of 64 per (b,e,h) in attn phase
#define KMAX 192      // LDS-staged key capacity (c ~ Binom(1024,1/8): P(c>192)~0)

__device__ __forceinline__ float wave_sum(float v) {
#pragma unroll
    for (int m = 32; m; m >>= 1) v += __shfl_xor(v, m, 64);
    return v;
}

// ---------------- Phase A: lists (bid 0-7) | transposes (8-71) | LN+gate fg (72-199) ----------------
__device__ void phaseA(char* smem, int bid, int tid,
    const float* __restrict__ Wq, const float* __restrict__ Wk,
    const float* __restrict__ Wv, const float* __restrict__ Wf,
    const float* __restrict__ fp, const float* __restrict__ x,
    const float* __restrict__ lnw, const float* __restrict__ lnb,
    const float* __restrict__ alpha,
    const float* __restrict__ Wg1, const float* __restrict__ bg1,
    const float* __restrict__ Wg2, const float* __restrict__ bg2,
    float* __restrict__ WfT, float* __restrict__ WqT,
    float* __restrict__ WkT, float* __restrict__ WvT,
    unsigned* __restrict__ cnt, unsigned* __restrict__ lst,
    float* __restrict__ fg)
{
    if (bid >= 200) return;
    if (bid < 8) {                        // expert token lists (1 wave)
        if (tid >= 64) return;
        int e = bid, l = tid;
        unsigned c = 0;
        for (int base = 0; base < NTOK; base += 64) {
            int n = base + l;
            int ee = (int)(fp[n] * 8.0f);
            ee = ee > 7 ? 7 : ee;
            bool in = (ee == e);
            unsigned long long m = __ballot(in);
            unsigned pos = (unsigned)__popcll(m & ((1ull << l) - 1ull));
            if (in) lst[e * NTOK + c + pos] = (unsigned)n;
            c += (unsigned)__popcll(m);
        }
        if (l == 0) cnt[e] = c;
        return;
    }
    float (*sh)[65] = (float(*)[65])smem;
    if (bid < 72) {                       // transposes
        const float* in;
        float* outp;
        int istride, ostride;
        if (bid < 24) {                   // Wf [512][128] -> WfT [128][512]
            int i = bid - 8, rt = i >> 1, ct2 = i & 1;
            in = Wf + (size_t)rt * 64 * DE + ct2 * 64;
            outp = WfT + (size_t)ct2 * 64 * DF + rt * 64;
            istride = DE; ostride = DF;
        } else {                          // Wq/Wk/Wv [128][64]/expert -> [64][128]
            int bb = bid - 24;
            int m = bb >> 4, e = (bb >> 1) & 7, dt = bb & 1;
            const float* W = (m == 0) ? Wq : (m == 1) ? Wk : Wv;
            float* WT      = (m == 0) ? WqT : (m == 1) ? WkT : WvT;
            in = W + (size_t)e * DE * S + (size_t)dt * 64 * S;
            outp = WT + (size_t)e * S * DE + dt * 64;
            istride = S; ostride = DE;
        }
        int cc = tid & 63, r0 = tid >> 6;
        for (int r = r0; r < 64; r += 4) sh[r][cc] = in[(size_t)r * istride + cc];
        __syncthreads();
        for (int c2 = r0; c2 < 64; c2 += 4)
            outp[(size_t)c2 * ostride + cc] = sh[cc][c2];
        return;
    }
    // f-compute: LN + gate, 4 tokens per wave
    float (*fw)[68] = (float(*)[68])smem;
    int wave = tid >> 6, lane = tid & 63;
    int t0 = (bid - 72) * 16 + wave * 4;  // token base (0..2047)
    int ej[4];
    for (int j = 0; j < 4; j++) {
        int t = t0 + j;
        int n = t & (NTOK - 1);
        const float* xr = x + (size_t)t * DF;
        float4 a  = *(const float4*)(xr + lane * 8);
        float4 b4 = *(const float4*)(xr + lane * 8 + 4);
        float s  = a.x + a.y + a.z + a.w + b4.x + b4.y + b4.z + b4.w;
        float ss = a.x*a.x + a.y*a.y + a.z*a.z + a.w*a.w
                 + b4.x*b4.x + b4.y*b4.y + b4.z*b4.z + b4.w*b4.w;
        s = wave_sum(s);
        ss = wave_sum(ss);
        float mu  = s * (1.0f / DF);
        float var = ss * (1.0f / DF) - mu * mu;
        float rs  = rsqrtf(var + 1e-5f);
        int e = (int)(fp[n] * 8.0f);
        e = e > 7 ? 7 : e;
        ej[j] = e;
        float f = (xr[e * 64 + lane] - mu) * rs * lnw[e * 64 + lane]
                + lnb[e * 64 + lane];
        fw[wave * 4 + j][lane] = f;
    }
    __syncthreads();
    int j = lane >> 4, h = lane & 15;
    int eg = ej[j];
    const float* wrow = Wg1 + ((size_t)eg * GH + h) * S;
    float g1 = bg1[eg * GH + h];
#pragma unroll 8
    for (int si = 0; si < S; si++) g1 += fw[wave * 4 + j][si] * wrow[si];
    g1 = 0.5f * g1 * (1.0f + erff(g1 * 0.70710678118654752f));
    float part = g1 * Wg2[eg * GH + h];
    part += __shfl_xor(part, 1, 64);
    part += __shfl_xor(part, 2, 64);
    part += __shfl_xor(part, 4, 64);
    part += __shfl_xor(part, 8, 64);
    float g2 = part + bg2[eg];
    float gate = 1.0f / (1.0f + __expf(-g2));
    float aw = 1.0f / (1.0f + __expf(-alpha[eg]));
    float gm = gate * aw + (1.0f - aw);
#pragma unroll
    for (int jj = 0; jj < 4; jj++) {
        float gmj = __shfl(gm, jj * 16, 64);
        fg[(size_t)(t0 + jj) * S + lane] = fw[wave * 4 + jj][lane] * gmj;
    }
}

// ---------------- Phase B: grouped QKV (4 tokens/wave share one weight stream) ----------------
__device__ void phaseB(char* smem, int bid, int tid,
    const float* __restrict__ fg,
    const float* __restrict__ WqT, const float* __restrict__ WkT,
    const float* __restrict__ WvT,
    const unsigned* __restrict__ cnt, const unsigned* __restrict__ lst,
    float* __restrict__ Q, float* __restrict__ K, float* __restrict__ V)
{
    float (*fsh)[4][68] = (float(*)[4][68])smem;
    int wave = tid >> 6, lane = tid & 63;
    int chunk = bid & 15;
    int e = (bid >> 4) & 7;
    int b = bid >> 7;
    int c = (int)cnt[e];
    if (chunk * 16 >= c) return;
    const unsigned* L = lst + e * NTOK;
    size_t wo = (size_t)e * S * DE;
    const float* Wqe = WqT + wo;
    const float* Wke = WkT + wo;
    const float* Wve = WvT + wo;
    int d2 = lane * 2;

    for (int it = 0; chunk * 16 + it * 256 < c; ++it) {
        int ib = it * 256 + chunk * 16 + wave * 4;
        int nj[4];
#pragma unroll
        for (int j = 0; j < 4; j++) {
            int ti = ib + j;
            int n = (int)L[ti < c ? ti : c - 1];
            nj[j] = n;
            fsh[wave][j][lane] = fg[(size_t)(b * NTOK + n) * S + lane];
        }
        float2 qa[4], ka[4], va[4];
#pragma unroll
        for (int j = 0; j < 4; j++) { qa[j] = {0,0}; ka[j] = {0,0}; va[j] = {0,0}; }
#pragma unroll 4
        for (int si = 0; si < S; si++) {
            float2 wq = *(const float2*)(Wqe + (size_t)si * DE + d2);
            float2 wk = *(const float2*)(Wke + (size_t)si * DE + d2);
            float2 wv = *(const float2*)(Wve + (size_t)si * DE + d2);
#pragma unroll
            for (int j = 0; j < 4; j++) {
                float fv = fsh[wave][j][si];
                qa[j].x += fv * wq.x; qa[j].y += fv * wq.y;
                ka[j].x += fv * wk.x; ka[j].y += fv * wk.y;
                va[j].x += fv * wv.x; va[j].y += fv * wv.y;
            }
        }
#pragma unroll
        for (int j = 0; j < 4; j++) {
            if (ib + j < c) {
                size_t ob = (size_t)(b * NTOK + nj[j]) * DE + d2;
                *(float2*)(Q + ob) = qa[j];
                *(float2*)(K + ob) = ka[j];
                *(float2*)(V + ob) = va[j];
            }
        }
    }
}

// ---------------- Phase C: block-diagonal flash attention, branchless 16-key chunks ----------------
__device__ void phaseC(char* smem, int bid, int tid,
    const float* __restrict__ Q, const float* __restrict__ K,
    const float* __restrict__ V,
    const unsigned* __restrict__ cnt, const unsigned* __restrict__ lst,
    const float* __restrict__ temp, float* __restrict__ F)
{
    float (*Ksh)[HD]  = (float(*)[HD])smem;                 // 12288 B
    float (*Vsh)[HD]  = (float(*)[HD])(smem + 12288);       // 12288 B
    float (*part)[18] = (float(*)[18])(smem + 24576);       // 18432 B [4*64][18]
    int qt = bid & (QT - 1);
    int beh = bid / QT;
    int b = beh >> 6, e = (beh >> 3) & 7, h = beh & 7;
    int c = (int)cnt[e];
    int qbase0 = qt * 64;
    if (qbase0 >= c) return;              // block-uniform
    int cs = c < KMAX ? c : KMAX;
    const unsigned* L = lst + e * NTOK;
    int wave = tid >> 6, lane = tid & 63;
    float inv_scale = 1.0f / (4.0f * fabsf(temp[0]));

    for (int j2 = tid; j2 < cs * 4; j2 += 256) {
        int i = j2 >> 2, comp = j2 & 3;
        int nk = (int)L[i];
        size_t rb = (size_t)(b * NTOK + nk) * DE + h * HD;
        ((float4*)Ksh[i])[comp] = ((const float4*)(K + rb))[comp];
        ((float4*)Vsh[i])[comp] = ((const float4*)(V + rb))[comp];
    }
    __syncthreads();

    int ck = (c + 3) >> 2;
    int k0 = wave * ck, k1 = min(c, k0 + ck);
    int kls = min(k1, cs);

    for (int qb = qbase0; qb < c; qb += QT * 64) {
        int qi = qb + lane;
        bool valid = qi < c;
        int nq = (int)L[valid ? qi : c - 1];
        const float* qp = Q + ((size_t)(b * NTOK + nq) * DE + h * HD);
        float q[16];
#pragma unroll
        for (int d4 = 0; d4 < 4; d4++) {
            float4 qv = ((const float4*)qp)[d4];
            q[4*d4] = qv.x * inv_scale; q[4*d4+1] = qv.y * inv_scale;
            q[4*d4+2] = qv.z * inv_scale; q[4*d4+3] = qv.w * inv_scale;
        }
        float m = -1e30f, l = 0.f;
        float acc[16];
#pragma unroll
        for (int d = 0; d < 16; d++) acc[d] = 0.f;

        for (int i0 = k0; i0 < kls; i0 += 16) {
            float sreg[16];
            float cmax = -1e30f;
#pragma unroll
            for (int j = 0; j < 16; j++) {
                int i = i0 + j;
                bool v = i < kls;
                int ii = v ? i : k0;
                const float4* kr = (const float4*)Ksh[ii];
                float4 ka = kr[0], kb = kr[1], kc = kr[2], kd = kr[3];
                float s = q[0]*ka.x + q[1]*ka.y + q[2]*ka.z + q[3]*ka.w
                        + q[4]*kb.x + q[5]*kb.y + q[6]*kb.z + q[7]*kb.w
                        + q[8]*kc.x + q[9]*kc.y + q[10]*kc.z + q[11]*kc.w
                        + q[12]*kd.x + q[13]*kd.y + q[14]*kd.z + q[15]*kd.w;
                s = v ? s : -1e30f;
                sreg[j] = s;
                cmax = fmaxf(cmax, s);
            }
            float mn = fmaxf(m, cmax);
            float r = __expf(m - mn);
            l *= r;
#pragma unroll
            for (int d = 0; d < 16; d++) acc[d] *= r;
            m = mn;
#pragma unroll
            for (int j = 0; j < 16; j++) {
                int i = i0 + j;
                bool v = i < kls;
                int ii = v ? i : k0;
                float p = __expf(sreg[j] - m);
                l += p;
                const float4* vr = (const float4*)Vsh[ii];
                float4 va = vr[0], vb = vr[1], vc = vr[2], vd = vr[3];
                acc[0] += p*va.x; acc[1] += p*va.y; acc[2] += p*va.z; acc[3] += p*va.w;
                acc[4] += p*vb.x; acc[5] += p*vb.y; acc[6] += p*vb.z; acc[7] += p*vb.w;
                acc[8] += p*vc.x; acc[9] += p*vc.y; acc[10]+= p*vc.z; acc[11]+= p*vc.w;
                acc[12]+= p*vd.x; acc[13]+= p*vd.y; acc[14]+= p*vd.z; acc[15]+= p*vd.w;
            }
        }
        for (int i = max(k0, cs); i < k1; i++) {   // global tail (c>KMAX only)
            int nk = (int)L[i];
            size_t rb = (size_t)(b * NTOK + nk) * DE + h * HD;
            const float* kp = K + rb;
            float s = 0.f;
            for (int dd = 0; dd < 16; dd++) s += q[dd] * kp[dd];
            float mn = fmaxf(m, s);
            float r = __expf(m - mn);
            l *= r;
#pragma unroll
            for (int d = 0; d < 16; d++) acc[d] *= r;
            m = mn;
            float p = __expf(s - m);
            l += p;
            const float* vp = V + rb;
#pragma unroll
            for (int d = 0; d < 16; d++) acc[d] += p * vp[d];
        }

        float* pp = part[wave * 64 + lane];
        pp[0] = m; pp[1] = l;
#pragma unroll
        for (int d = 0; d < 16; d++) pp[2 + d] = acc[d];
        __syncthreads();

        if (wave == 0) {
            float M = part[lane][0];
            M = fmaxf(M, part[64 + lane][0]);
            M = fmaxf(M, part[128 + lane][0]);
            M = fmaxf(M, part[192 + lane][0]);
            float Lt = 0.f;
            float o[16];
#pragma unroll
            for (int d = 0; d < 16; d++) o[d] = 0.f;
#pragma unroll
            for (int w = 0; w < 4; w++) {
                const float* qq = part[w * 64 + lane];
                float r = __expf(qq[0] - M);
                Lt += qq[1] * r;
#pragma unroll
                for (int d = 0; d < 16; d++) o[d] += qq[2 + d] * r;
            }
            if (valid) {
                float il = 1.0f / Lt;
                float* op = F + (size_t)(b * NTOK + nq) * DE + h * HD;
#pragma unroll
                for (int d4 = 0; d4 < 4; d4++)
                    ((float4*)op)[d4] = make_float4(o[4*d4]*il, o[4*d4+1]*il,
                                                    o[4*d4+2]*il, o[4*d4+3]*il);
            }
        }
        __syncthreads();
    }
}

// ---------------- Phase D: proj (coalesced WfT) + bias + residual, 8 tokens/block ----------------
__device__ void phaseD(char* smem, int bid, int tid,
    const float* __restrict__ x, const float* __restrict__ F,
    const float* __restrict__ WfT, const float* __restrict__ bf,
    float* __restrict__ out)
{
    float (*fr)[DE] = (float(*)[DE])smem;
    int t0 = bid * 8;
    ((float4*)fr)[tid] = ((const float4*)(F + (size_t)t0 * DE))[tid];
    __syncthreads();
    float acc0[8], acc1[8];
    float b0 = bf[tid], b1 = bf[tid + 256];
#pragma unroll
    for (int tk = 0; tk < 8; tk++) { acc0[tk] = b0; acc1[tk] = b1; }
#pragma unroll 4
    for (int k = 0; k < DE; k++) {
        float w0 = WfT[(size_t)k * DF + tid];
        float w1 = WfT[(size_t)k * DF + tid + 256];
#pragma unroll
        for (int tk = 0; tk < 8; tk++) {
            float fv = fr[tk][k];
            acc0[tk] += fv * w0;
            acc1[tk] += fv * w1;
        }
    }
#pragma unroll
    for (int tk = 0; tk < 8; tk++) {
        size_t rb = (size_t)(t0 + tk) * DF;
        out[rb + tid]       = x[rb + tid]       + acc0[tk];
        out[rb + tid + 256] = x[rb + tid + 256] + acc1[tk];
    }
}

// ---------------- mega kernel: all phases, cooperative grid sync ----------------
__global__ __launch_bounds__(256) void k_mega(
    const float* x, const float* fp, const float* lnw, const float* lnb,
    const float* alpha, const float* Wg1, const float* bg1, const float* Wg2,
    const float* bg2, const float* Wq, const float* Wk, const float* Wv,
    const float* temp, const float* Wf, const float* bf, float* out,
    float* WfT, float* WqT, float* WkT, float* WvT,
    unsigned* cnt, unsigned* lst, float* fg,
    float* Qb, float* Kb, float* Vb, float* Fb)
{
    __shared__ __align__(16) char smem[43520];
    cg::grid_group grid = cg::this_grid();
    int bid = blockIdx.x, tid = threadIdx.x;
    phaseA(smem, bid, tid, Wq, Wk, Wv, Wf, fp, x, lnw, lnb, alpha,
           Wg1, bg1, Wg2, bg2, WfT, WqT, WkT, WvT, cnt, lst, fg);
    __threadfence();
    grid.sync();
    phaseB(smem, bid, tid, fg, WqT, WkT, WvT, cnt, lst, Qb, Kb, Vb);
    __threadfence();
    grid.sync();
    phaseC(smem, bid, tid, Qb, Kb, Vb, cnt, lst, temp, Fb);
    __threadfence();
    grid.sync();
    phaseD(smem, bid, tid, x, Fb, WfT, bf, out);
}

// ---------------- fallback: the same phases as 4 separate kernels ----------------
__global__ __launch_bounds__(256) void k_pA(
    const float* Wq, const float* Wk, const float* Wv, const float* Wf,
    const float* fp, const float* x, const float* lnw, const float* lnb,
    const float* alpha, const float* Wg1, const float* bg1, const float* Wg2,
    const float* bg2, float* WfT, float* WqT, float* WkT, float* WvT,
    unsigned* cnt, unsigned* lst, float* fg) {
    __shared__ __align__(16) char smem[16896];
    phaseA(smem, blockIdx.x, threadIdx.x, Wq, Wk, Wv, Wf, fp, x, lnw, lnb,
           alpha, Wg1, bg1, Wg2, bg2, WfT, WqT, WkT, WvT, cnt, lst, fg);
}
__global__ __launch_bounds__(256) void k_pB(
    const float* fg, const float* WqT, const float* WkT, const float* WvT,
    const unsigned* cnt, const unsigned* lst, float* Q, float* K, float* V) {
    __shared__ __align__(16) char smem[4608];
    phaseB(smem, blockIdx.x, threadIdx.x, fg, WqT, WkT, WvT, cnt, lst, Q, K, V);
}
__global__ __launch_bounds__(256) void k_pC(
    const float* Q, const float* K, const float* V,
    const unsigned* cnt, const unsigned* lst, const float* temp, float* F) {
    __shared__ __align__(16) char smem[43520];
    phaseC(smem, blockIdx.x, threadIdx.x, Q, K, V, cnt, lst, temp, F);
}
__global__ __launch_bounds__(256) void k_pD(
    const float* x, const float* F, const float* WfT, const float* bf,
    float* out) {
    __shared__ __align__(16) char smem[4096];
    phaseD(smem, blockIdx.x, threadIdx.x, x, F, WfT, bf, out);
}

extern "C" void kernel_launch(void* const* d_in, const int* in_sizes, int n_in,
                              void* d_out, int out_size, void* d_ws, size_t ws_size,
                              hipStream_t stream) {
    (void)in_sizes; (void)n_in; (void)out_size; (void)ws_size;
    const float* x     = (const float*)d_in[0];
    const float* fp    = (const float*)d_in[1];
    const float* lnw   = (const float*)d_in[2];
    const float* lnb   = (const float*)d_in[3];
    const float* alpha = (const float*)d_in[4];
    const float* Wg1   = (const float*)d_in[5];
    const float* bg1   = (const float*)d_in[6];
    const float* Wg2   = (const float*)d_in[7];
    const float* bg2   = (const float*)d_in[8];
    const float* Wq    = (const float*)d_in[9];
    const float* Wk    = (const float*)d_in[10];
    const float* Wv    = (const float*)d_in[11];
    const float* temp  = (const float*)d_in[12];
    const float* Wf    = (const float*)d_in[13];
    const float* bf    = (const float*)d_in[14];
    float* out = (float*)d_out;

    char* ws = (char*)d_ws;
    unsigned* cnt = (unsigned*)ws;                     // 1 KB
    unsigned* lst = (unsigned*)(ws + 1024);            // 32 KB
    float* fg  = (float*)(ws + 65536);                 // 512 KB
    float* Qb  = fg + (size_t)B * NTOK * S;            // 1 MB each
    float* Kb  = Qb + (size_t)B * NTOK * DE;
    float* Vb  = Kb + (size_t)B * NTOK * DE;
    float* Fb  = Vb + (size_t)B * NTOK * DE;
    float* WfT = Fb + (size_t)B * NTOK * DE;           // 256 KB
    float* WqT = WfT + (size_t)DE * DF;                // 256 KB each
    float* WkT = WqT + (size_t)E * S * DE;
    float* WvT = WkT + (size_t)E * S * DE;

    void* args[] = {
        (void*)&x, (void*)&fp, (void*)&lnw, (void*)&lnb, (void*)&alpha,
        (void*)&Wg1, (void*)&bg1, (void*)&Wg2, (void*)&bg2,
        (void*)&Wq, (void*)&Wk, (void*)&Wv, (void*)&temp, (void*)&Wf,
        (void*)&bf, (void*)&out,
        (void*)&WfT, (void*)&WqT, (void*)&WkT, (void*)&WvT,
        (void*)&cnt, (void*)&lst, (void*)&fg,
        (void*)&Qb, (void*)&Kb, (void*)&Vb, (void*)&Fb };
    hipError_t err = hipLaunchCooperativeKernel(
        (const void*)k_mega, dim3(256), dim3(256), args, 0, stream);
    if (err != hipSuccess) {
        // fallback: identical phases as 4 regular graph nodes
        hipLaunchKernelGGL(k_pA, dim3(200), dim3(256), 0, stream,
                           Wq, Wk, Wv, Wf, fp, x, lnw, lnb, alpha,
                           Wg1, bg1, Wg2, bg2, WfT, WqT, WkT, WvT, cnt, lst, fg);
        hipLaunchKernelGGL(k_pB, dim3(256), dim3(256), 0, stream,
                           fg, WqT, WkT, WvT, cnt, lst, Qb, Kb, Vb);
        hipLaunchKernelGGL(k_pC, dim3(256), dim3(256), 0, stream,
                           Qb, Kb, Vb, cnt, lst, temp, Fb);
        hipLaunchKernelGGL(k_pD, dim3(256), dim3(256), 0, stream,
                           x, Fb, WfT, bf, out);
    }
}

// Round 9
// 53.602 us; speedup vs baseline: 4.2993x; 4.2993x over previous
//
#include <hip/hip_runtime.h>
#include <math.h>

#define E 8
#define DF 512
#define DE 128
#define H 8
#define S 64
#define GH 16
#define HD 16
#define B 2
#define NTOK 1024
#define KMAX 256      // staged key capacity (c ~ Binom(1024,1/8), max realistic ~190)

__device__ __forceinline__ float wave_sum(float v) {
#pragma unroll
    for (int m = 32; m; m >>= 1) v += __shfl_xor(v, m, 64);
    return v;
}

// ---- kernel 1: prep ----
// bid 0-7: expert lists | 8-71: transposes (WfT, WqT/WkT/WvT) | 72-583: LN+gate -> fg (1 token/wave)
__global__ __launch_bounds__(256) void k_prep(
    const float* __restrict__ Wq, const float* __restrict__ Wk,
    const float* __restrict__ Wv, const float* __restrict__ Wf,
    const float* __restrict__ fp, const float* __restrict__ x,
    const float* __restrict__ lnw, const float* __restrict__ lnb,
    const float* __restrict__ alpha,
    const float* __restrict__ Wg1, const float* __restrict__ bg1,
    const float* __restrict__ Wg2, const float* __restrict__ bg2,
    float* __restrict__ WfT, float* __restrict__ WqT, float* __restrict__ WkT,
    float* __restrict__ WvT, unsigned* __restrict__ cnt,
    unsigned* __restrict__ lst, float* __restrict__ fg) {
    __shared__ __align__(16) float sh[64][65];
    int bid = blockIdx.x, tid = threadIdx.x;
    if (bid < 8) {                        // expert token lists (1 wave)
        if (tid >= 64) return;
        int e = bid, l = tid;
        unsigned c = 0;
        for (int base = 0; base < NTOK; base += 64) {
            int n = base + l;
            int ee = (int)(fp[n] * 8.0f);
            ee = ee > 7 ? 7 : ee;
            bool in = (ee == e);
            unsigned long long m = __ballot(in);
            unsigned pos = (unsigned)__popcll(m & ((1ull << l) - 1ull));
            if (in) lst[e * NTOK + c + pos] = (unsigned)n;
            c += (unsigned)__popcll(m);
        }
        if (l == 0) cnt[e] = c;
        return;
    }
    if (bid < 72) {                       // transposes
        const float* in;
        float* outp;
        int istride, ostride;
        if (bid < 24) {                   // Wf [512][128] -> WfT [128][512]
            int i = bid - 8, rt = i >> 1, ct2 = i & 1;
            in = Wf + (size_t)rt * 64 * DE + ct2 * 64;
            outp = WfT + (size_t)ct2 * 64 * DF + rt * 64;
            istride = DE; ostride = DF;
        } else {                          // Wq/Wk/Wv [128][64]/expert -> [64][128]
            int bb = bid - 24;
            int m = bb >> 4, e = (bb >> 1) & 7, dt = bb & 1;
            const float* W = (m == 0) ? Wq : (m == 1) ? Wk : Wv;
            float* WT      = (m == 0) ? WqT : (m == 1) ? WkT : WvT;
            in = W + (size_t)e * DE * S + (size_t)dt * 64 * S;
            outp = WT + (size_t)e * S * DE + dt * 64;
            istride = S; ostride = DE;
        }
        int cc = tid & 63, r0 = tid >> 6;
        for (int r = r0; r < 64; r += 4) sh[r][cc] = in[(size_t)r * istride + cc];
        __syncthreads();
        for (int c2 = r0; c2 < 64; c2 += 4)
            outp[(size_t)c2 * ostride + cc] = sh[cc][c2];
        return;
    }
    // LN + gate, 1 token per wave
    float (*fsh)[64] = (float(*)[64])sh;  // [4 waves][64]
    int wave = tid >> 6, lane = tid & 63;
    int t = (bid - 72) * 4 + wave;        // 0..2047
    int n = t & (NTOK - 1);
    const float* xr = x + (size_t)t * DF;
    float4 a  = *(const float4*)(xr + lane * 8);
    float4 b4 = *(const float4*)(xr + lane * 8 + 4);
    float s  = a.x + a.y + a.z + a.w + b4.x + b4.y + b4.z + b4.w;
    float ss = a.x*a.x + a.y*a.y + a.z*a.z + a.w*a.w
             + b4.x*b4.x + b4.y*b4.y + b4.z*b4.z + b4.w*b4.w;
    s = wave_sum(s);
    ss = wave_sum(ss);
    float mu  = s * (1.0f / DF);
    float var = ss * (1.0f / DF) - mu * mu;
    float rs  = rsqrtf(var + 1e-5f);
    int e = (int)(fp[n] * 8.0f);
    e = e > 7 ? 7 : e;
    float f = (xr[e * 64 + lane] - mu) * rs * lnw[e * 64 + lane]
            + lnb[e * 64 + lane];
    fsh[wave][lane] = f;
    __syncthreads();
    // gate: lane -> (h = lane&15, si-quarter = lane>>4)
    int h = lane & 15, sb = (lane >> 4) * 16;
    const float* wg1 = Wg1 + ((size_t)e * GH + h) * S;
    float g1p = 0.f;
#pragma unroll
    for (int si = 0; si < 16; si++) g1p += fsh[wave][sb + si] * wg1[sb + si];
    g1p += __shfl_xor(g1p, 16, 64);
    g1p += __shfl_xor(g1p, 32, 64);
    float g1 = g1p + bg1[e * GH + h];
    g1 = 0.5f * g1 * (1.0f + erff(g1 * 0.70710678118654752f));
    float part = g1 * Wg2[e * GH + h];
    part += __shfl_xor(part, 1, 64);
    part += __shfl_xor(part, 2, 64);
    part += __shfl_xor(part, 4, 64);
    part += __shfl_xor(part, 8, 64);
    float g2 = part + bg2[e];
    float gate = 1.0f / (1.0f + __expf(-g2));
    float aw = 1.0f / (1.0f + __expf(-alpha[e]));
    float gm = gate * aw + (1.0f - aw);
    fg[(size_t)t * S + lane] = f * gm;
}

// ---- kernel 2: grouped QKV, 4 tokens/block, 4 waves = (d-half x s-half) quadrants ----
__global__ __launch_bounds__(256) void k_qkv(
    const float* __restrict__ fg,
    const float* __restrict__ WqT, const float* __restrict__ WkT,
    const float* __restrict__ WvT,
    const unsigned* __restrict__ cnt, const unsigned* __restrict__ lst,
    float* __restrict__ Q, float* __restrict__ K, float* __restrict__ V) {
    __shared__ float fsh[4][64];          // 4 tokens x 64 si (1 KB)
    __shared__ float pmrg[2][4][3][64];   // [dh][tok][mat][d] partials from sh=1 (6 KB)
    int tid = threadIdx.x, wave = tid >> 6, lane = tid & 63;
    int bid = blockIdx.x;                 // b*512 + e*64 + chunk
    int chunk = bid & 63;
    int e = (bid >> 6) & 7;
    int b = bid >> 9;
    int c = (int)cnt[e];
    if (chunk * 4 >= c) return;           // block-uniform
    const unsigned* L = lst + e * NTOK;
    int dh = wave >> 1, sh = wave & 1;
    size_t wo = (size_t)e * S * DE + (size_t)(sh * 32) * DE + dh * 64 + lane;
    const float* Wqp = WqT + wo;
    const float* Wkp = WkT + wo;
    const float* Wvp = WvT + wo;

    for (int ib = chunk * 4; ib < c; ib += 256) {   // 64 chunks x 4 slots
        // stage 4 tokens' fg rows
        {
            int ti = ib + (tid >> 6);
            int n = (int)L[ti < c ? ti : c - 1];
            fsh[tid >> 6][tid & 63] = fg[(size_t)(b * NTOK + n) * S + (tid & 63)];
        }
        __syncthreads();
        float qa[4] = {0,0,0,0}, ka[4] = {0,0,0,0}, va[4] = {0,0,0,0};
#pragma unroll 8
        for (int s = 0; s < 32; s++) {
            float wq = Wqp[(size_t)s * DE];
            float wk = Wkp[(size_t)s * DE];
            float wv = Wvp[(size_t)s * DE];
#pragma unroll
            for (int j = 0; j < 4; j++) {
                float fv = fsh[j][sh * 32 + s];
                qa[j] += fv * wq; ka[j] += fv * wk; va[j] += fv * wv;
            }
        }
        if (sh == 1) {
#pragma unroll
            for (int j = 0; j < 4; j++) {
                pmrg[dh][j][0][lane] = qa[j];
                pmrg[dh][j][1][lane] = ka[j];
                pmrg[dh][j][2][lane] = va[j];
            }
        }
        __syncthreads();
        if (sh == 0) {
#pragma unroll
            for (int j = 0; j < 4; j++) {
                if (ib + j < c) {
                    int n = (int)L[ib + j];
                    size_t ob = (size_t)(b * NTOK + n) * DE + dh * 64 + lane;
                    Q[ob] = qa[j] + pmrg[dh][j][0][lane];
                    K[ob] = ka[j] + pmrg[dh][j][1][lane];
                    V[ob] = va[j] + pmrg[dh][j][2][lane];
                }
            }
        }
        __syncthreads();
    }
}

// ---- kernel 3: flash attention, block = (b,e,h,16-query chunk), lane = (query, key-16th) ----
__global__ __launch_bounds__(256) void k_attn(
    const float* __restrict__ Q, const float* __restrict__ K,
    const float* __restrict__ V, const unsigned* __restrict__ cnt,
    const unsigned* __restrict__ lst, const float* __restrict__ temp,
    float* __restrict__ F) {
    __shared__ float Ksh[KMAX][HD];       // 16 KB
    __shared__ float Vsh[KMAX][HD];       // 16 KB
    __shared__ float part[4][16][18];     // 4.6 KB
    int bid = blockIdx.x;                 // b*1024 + e*128 + h*16 + qc
    int qc = bid & 15;
    int h = (bid >> 4) & 7;
    int e = (bid >> 7) & 7;
    int b = bid >> 10;
    int c = (int)cnt[e];
    if (qc * 16 >= c) return;             // block-uniform
    int cs = c < KMAX ? c : KMAX;
    const unsigned* L = lst + e * NTOK;
    int tid = threadIdx.x, wave = tid >> 6, lane = tid & 63;
    int q16 = lane & 15, kq = lane >> 4;
    float inv_scale = 1.0f / (4.0f * fabsf(temp[0]));

    for (int j2 = tid; j2 < cs * 4; j2 += 256) {
        int i = j2 >> 2, comp = j2 & 3;
        int nk = (int)L[i];
        size_t rb = (size_t)(b * NTOK + nk) * DE + h * HD;
        ((float4*)Ksh[i])[comp] = ((const float4*)(K + rb))[comp];
        ((float4*)Vsh[i])[comp] = ((const float4*)(V + rb))[comp];
    }
    __syncthreads();

    int cl = (cs + 15) >> 4;              // staged keys per lane (<=16)
    int k0 = (wave * 4 + kq) * cl;
    int klim = min(cs, k0 + cl);

    for (int qb = qc * 16; qb < c; qb += 256) {     // 1 iter normally
        int qi = qb + q16;
        bool valid = qi < c;
        int nq = (int)L[valid ? qi : c - 1];
        const float* qp = Q + ((size_t)(b * NTOK + nq) * DE + h * HD);
        float q[16];
#pragma unroll
        for (int d4 = 0; d4 < 4; d4++) {
            float4 qv = ((const float4*)qp)[d4];
            q[4*d4] = qv.x * inv_scale; q[4*d4+1] = qv.y * inv_scale;
            q[4*d4+2] = qv.z * inv_scale; q[4*d4+3] = qv.w * inv_scale;
        }
        // single-chunk softmax over this lane's <=16 staged keys
        float sreg[16];
        float m = -1e30f;
#pragma unroll
        for (int j = 0; j < 16; j++) {
            int i = k0 + j;
            bool v = i < klim;
            int ii = v ? i : k0;
            const float4* kr = (const float4*)Ksh[ii];
            float4 ka = kr[0], kb = kr[1], kc = kr[2], kd = kr[3];
            float sc = q[0]*ka.x + q[1]*ka.y + q[2]*ka.z + q[3]*ka.w
                     + q[4]*kb.x + q[5]*kb.y + q[6]*kb.z + q[7]*kb.w
                     + q[8]*kc.x + q[9]*kc.y + q[10]*kc.z + q[11]*kc.w
                     + q[12]*kd.x + q[13]*kd.y + q[14]*kd.z + q[15]*kd.w;
            sc = v ? sc : -1e30f;
            sreg[j] = sc;
            m = fmaxf(m, sc);
        }
        float l = 0.f;
        float acc[16];
#pragma unroll
        for (int d = 0; d < 16; d++) acc[d] = 0.f;
#pragma unroll
        for (int j = 0; j < 16; j++) {
            int i = k0 + j;
            int ii = i < klim ? i : k0;
            float p = __expf(sreg[j] - m);   // 0 for invalid slots
            l += p;
            const float4* vr = (const float4*)Vsh[ii];
            float4 va = vr[0], vb = vr[1], vc = vr[2], vd = vr[3];
            acc[0] += p*va.x; acc[1] += p*va.y; acc[2] += p*va.z; acc[3] += p*va.w;
            acc[4] += p*vb.x; acc[5] += p*vb.y; acc[6] += p*vb.z; acc[7] += p*vb.w;
            acc[8] += p*vc.x; acc[9] += p*vc.y; acc[10]+= p*vc.z; acc[11]+= p*vc.w;
            acc[12]+= p*vd.x; acc[13]+= p*vd.y; acc[14]+= p*vd.z; acc[15]+= p*vd.w;
        }
        // global tail (cs < c only; never taken normally)
        for (int i = cs + (wave * 4 + kq); i < c; i += 16) {
            int nk = (int)L[i];
            size_t rb = (size_t)(b * NTOK + nk) * DE + h * HD;
            const float* kp = K + rb;
            float sc = 0.f;
            for (int dd = 0; dd < 16; dd++) sc += q[dd] * kp[dd];
            float mn = fmaxf(m, sc);
            float r = __expf(m - mn);
            l *= r;
#pragma unroll
            for (int d = 0; d < 16; d++) acc[d] *= r;
            m = mn;
            float p = __expf(sc - m);
            l += p;
            const float* vp = V + rb;
#pragma unroll
            for (int d = 0; d < 16; d++) acc[d] += p * vp[d];
        }
        // butterfly merge over the 4 key-16ths sharing this query (lane bits 4,5)
#pragma unroll
        for (int mask = 16; mask <= 32; mask <<= 1) {
            float mo = __shfl_xor(m, mask, 64);
            float lo = __shfl_xor(l, mask, 64);
            float mn = fmaxf(m, mo);
            float e1 = __expf(m - mn), e2 = __expf(mo - mn);
            l = l * e1 + lo * e2;
#pragma unroll
            for (int d = 0; d < 16; d++) {
                float ao = __shfl_xor(acc[d], mask, 64);
                acc[d] = acc[d] * e1 + ao * e2;
            }
            m = mn;
        }
        if (lane < 16) {
            float* pp = part[wave][lane];
            pp[0] = m; pp[1] = l;
#pragma unroll
            for (int d = 0; d < 16; d++) pp[2 + d] = acc[d];
        }
        __syncthreads();
        if (wave == 0 && lane < 16) {
            float M = part[0][lane][0];
            M = fmaxf(M, part[1][lane][0]);
            M = fmaxf(M, part[2][lane][0]);
            M = fmaxf(M, part[3][lane][0]);
            float Lt = 0.f;
            float o[16];
#pragma unroll
            for (int d = 0; d < 16; d++) o[d] = 0.f;
#pragma unroll
            for (int w = 0; w < 4; w++) {
                const float* qq = part[w][lane];
                float r = __expf(qq[0] - M);
                Lt += qq[1] * r;
#pragma unroll
                for (int d = 0; d < 16; d++) o[d] += qq[2 + d] * r;
            }
            if (valid) {
                float il = 1.0f / Lt;
                float* op = F + (size_t)(b * NTOK + nq) * DE + h * HD;
#pragma unroll
                for (int d4 = 0; d4 < 4; d4++)
                    ((float4*)op)[d4] = make_float4(o[4*d4]*il, o[4*d4+1]*il,
                                                    o[4*d4+2]*il, o[4*d4+3]*il);
            }
        }
        __syncthreads();
    }
}

// ---- kernel 4: proj, 512 threads, 8 tokens, k-split 2-way with LDS merge ----
__global__ __launch_bounds__(512) void k_proj(
    const float* __restrict__ x, const float* __restrict__ F,
    const float* __restrict__ WfT, const float* __restrict__ bf,
    float* __restrict__ out) {
    __shared__ float fr[8][DE];           // 4 KB
    __shared__ float pp[8][DF];           // 16 KB (kh=1 partials)
    int t0 = blockIdx.x * 8;
    int tid = threadIdx.x;
    if (tid < 256) ((float4*)fr)[tid] = ((const float4*)(F + (size_t)t0 * DE))[tid];
    __syncthreads();
    int kh = tid >> 8, tt = tid & 255;
    float acc0[8], acc1[8];
#pragma unroll
    for (int tk = 0; tk < 8; tk++) { acc0[tk] = 0.f; acc1[tk] = 0.f; }
    int kb = kh * 64;
#pragma unroll 4
    for (int k = kb; k < kb + 64; k++) {
        float w0 = WfT[(size_t)k * DF + tt];
        float w1 = WfT[(size_t)k * DF + tt + 256];
#pragma unroll
        for (int tk = 0; tk < 8; tk++) {
            float fv = fr[tk][k];
            acc0[tk] += fv * w0;
            acc1[tk] += fv * w1;
        }
    }
    if (kh == 1) {
#pragma unroll
        for (int tk = 0; tk < 8; tk++) {
            pp[tk][tt]       = acc0[tk];
            pp[tk][tt + 256] = acc1[tk];
        }
    }
    __syncthreads();
    if (kh == 0) {
        float b0 = bf[tt], b1 = bf[tt + 256];
#pragma unroll
        for (int tk = 0; tk < 8; tk++) {
            size_t rb = (size_t)(t0 + tk) * DF;
            out[rb + tt]       = x[rb + tt]       + b0 + acc0[tk] + pp[tk][tt];
            out[rb + tt + 256] = x[rb + tt + 256] + b1 + acc1[tk] + pp[tk][tt + 256];
        }
    }
}

extern "C" void kernel_launch(void* const* d_in, const int* in_sizes, int n_in,
                              void* d_out, int out_size, void* d_ws, size_t ws_size,
                              hipStream_t stream) {
    (void)in_sizes; (void)n_in; (void)out_size; (void)ws_size;
    const float* x     = (const float*)d_in[0];
    const float* fp    = (const float*)d_in[1];
    const float* lnw   = (const float*)d_in[2];
    const float* lnb   = (const float*)d_in[3];
    const float* alpha = (const float*)d_in[4];
    const float* Wg1   = (const float*)d_in[5];
    const float* bg1   = (const float*)d_in[6];
    const float* Wg2   = (const float*)d_in[7];
    const float* bg2   = (const float*)d_in[8];
    const float* Wq    = (const float*)d_in[9];
    const float* Wk    = (const float*)d_in[10];
    const float* Wv    = (const float*)d_in[11];
    const float* temp  = (const float*)d_in[12];
    const float* Wf    = (const float*)d_in[13];
    const float* bf    = (const float*)d_in[14];
    float* out = (float*)d_out;

    char* ws = (char*)d_ws;
    unsigned* cnt = (unsigned*)ws;                     // 1 KB
    unsigned* lst = (unsigned*)(ws + 1024);            // 32 KB
    float* fg  = (float*)(ws + 65536);                 // 512 KB
    float* Qb  = fg + (size_t)B * NTOK * S;            // 1 MB each
    float* Kb  = Qb + (size_t)B * NTOK * DE;
    float* Vb  = Kb + (size_t)B * NTOK * DE;
    float* Fb  = Vb + (size_t)B * NTOK * DE;
    float* WfT = Fb + (size_t)B * NTOK * DE;           // 256 KB
    float* WqT = WfT + (size_t)DE * DF;                // 256 KB each
    float* WkT = WqT + (size_t)E * S * DE;
    float* WvT = WkT + (size_t)E * S * DE;

    hipLaunchKernelGGL(k_prep, dim3(584), dim3(256), 0, stream,
                       Wq, Wk, Wv, Wf, fp, x, lnw, lnb, alpha, Wg1, bg1, Wg2, bg2,
                       WfT, WqT, WkT, WvT, cnt, lst, fg);
    hipLaunchKernelGGL(k_qkv, dim3(1024), dim3(256), 0, stream,
                       fg, WqT, WkT, WvT, cnt, lst, Qb, Kb, Vb);
    hipLaunchKernelGGL(k_attn, dim3(2048), dim3(256), 0, stream,
                       Qb, Kb, Vb, cnt, lst, temp, Fb);
    hipLaunchKernelGGL(k_proj, dim3(B * NTOK / 8), dim3(512), 0, stream,
                       x, Fb, WfT, bf, out);
}